// Round 3
// baseline (1176.087 us; speedup 1.0000x reference)
//
#include <hip/hip_runtime.h>
#include <hip/hip_bf16.h>

#define BEV 180
#define NPOS (BEV * BEV)   // 32400
#define MTOT (2 * NPOS)    // 64800
#define IH 64
#define IW 176
#define CIMG 256
#define XTILES 12          // 12*16 = 192 >= 180
#define YTILES 23          // 23*8  = 184 >= 180
#define MBLK (XTILES * YTILES * 2)  // 552

typedef __attribute__((ext_vector_type(8))) short bf16x8;
typedef __attribute__((ext_vector_type(4))) float f32x4;

__device__ __forceinline__ void gload_lds16(const void* g, void* l) {
  __builtin_amdgcn_global_load_lds(
      (const __attribute__((address_space(1))) void*)g,
      (__attribute__((address_space(3))) void*)l, 16, 0, 0);
}

// ---------------- zero page ----------------
__global__ void k_zero(unsigned long long* p) { p[threadIdx.x] = 0ULL; }

// ---------------- generic fp32 [B][R][CL] -> [B][CL][R] transpose ----------------
template <typename OT>
__device__ __forceinline__ OT conv_out(float v);
template <>
__device__ __forceinline__ float conv_out<float>(float v) { return v; }
template <>
__device__ __forceinline__ __hip_bfloat16 conv_out<__hip_bfloat16>(float v) { return __float2bfloat16(v); }

template <typename OT>
__global__ void k_transpose(const float* __restrict__ in, OT* __restrict__ out, int R, int CL) {
  __shared__ float tile[32][33];
  const float* inb = in + (size_t)blockIdx.z * R * CL;
  OT* outb = out + (size_t)blockIdx.z * R * CL;
  int c0 = blockIdx.x * 32, r0 = blockIdx.y * 32;
  int tx = threadIdx.x, ty = threadIdx.y;
#pragma unroll
  for (int i = 0; i < 32; i += 8) {
    int r = r0 + ty + i, c = c0 + tx;
    tile[ty + i][tx] = (r < R && c < CL) ? inb[(size_t)r * CL + c] : 0.f;
  }
  __syncthreads();
#pragma unroll
  for (int i = 0; i < 32; i += 8) {
    int c = c0 + ty + i, r = r0 + tx;
    if (c < CL && r < R) outb[(size_t)c * R + r] = conv_out<OT>(tile[tx][ty + i]);
  }
}

// ---------------- projection + bilinear sample -> image_bev NHWC bf16 ----------------
__global__ void k_sample(const float* __restrict__ imgT, const float* __restrict__ l2i,
                         __hip_bfloat16* __restrict__ out) {
  int blk = blockIdx.x;
  int b = blk / NPOS, rem = blk - b * NPOS;
  int hy = rem / BEV, wx = rem - hy * BEV;
  int c = threadIdx.x;
  float gx = -54.f + 0.3f + 0.6f * (float)wx;
  float gy = -54.f + 0.3f + 0.6f * (float)hy;
  const float* L = l2i + b * 12;
  const float* img = imgT + (size_t)b * (IH * IW * CIMG);
  float acc = 0.f, vcnt = 0.f;
#pragma unroll
  for (int zi = 0; zi < 3; ++zi) {
    float z = (float)(zi - 1);
    float p0 = L[0] * gx + L[1] * gy + L[2] * z + L[3];
    float p1 = L[4] * gx + L[5] * gy + L[6] * z + L[7];
    float p2 = L[8] * gx + L[9] * gy + L[10] * z + L[11];
    float d = fmaxf(p2, 1e-5f);
    float px = p0 / d, py = p1 / d;
    if (px >= 0.f && px < 704.f && py >= 0.f && py < 256.f && p2 > 1e-5f) {
      vcnt += 1.f;
      float ix = px * 0.25f - 0.5f, iy = py * 0.25f - 0.5f;
      float xf = floorf(ix), yf = floorf(iy);
      float wx1 = ix - xf, wy1 = iy - yf;
      float wx0 = 1.f - wx1, wy0 = 1.f - wy1;
      int x0 = (int)xf, y0 = (int)yf;
      int x1 = x0 + 1, y1 = y0 + 1;
      bool bx0 = (unsigned)x0 < IW, bx1 = (unsigned)x1 < IW;
      bool by0 = (unsigned)y0 < IH, by1 = (unsigned)y1 < IH;
      float s = 0.f;
      if (bx0 && by0) s += wx0 * wy0 * img[((size_t)y0 * IW + x0) * CIMG + c];
      if (bx1 && by0) s += wx1 * wy0 * img[((size_t)y0 * IW + x1) * CIMG + c];
      if (bx0 && by1) s += wx0 * wy1 * img[((size_t)y1 * IW + x0) * CIMG + c];
      if (bx1 && by1) s += wx1 * wy1 * img[((size_t)y1 * IW + x1) * CIMG + c];
      acc += s;
    }
  }
  out[(size_t)blk * CIMG + c] = __float2bfloat16(acc / fmaxf(vcnt, 1.f));
}

// ---------------- weight pack: w[co][ci][tap] fp32 -> wp[tap][co][ci] bf16 ----------------
__global__ void k_packw(const float* __restrict__ w, __hip_bfloat16* __restrict__ wp,
                        int Co, int Ci, int T) {
  size_t idx = (size_t)blockIdx.x * 256 + threadIdx.x;
  size_t tot = (size_t)Co * Ci * T;
  if (idx >= tot) return;
  int ci = (int)(idx % Ci);
  size_t r = idx / Ci;
  int co = (int)(r % Co);
  int tap = (int)(r / Co);
  wp[idx] = __float2bfloat16(w[((size_t)co * Ci + ci) * T + tap]);
}

// ---------------- BN fold: [4][C] -> [2][C] (scale, bias) ----------------
__global__ void k_packbn(const float* __restrict__ bn, float* __restrict__ sb, int C) {
  int i = blockIdx.x * blockDim.x + threadIdx.x;
  if (i >= C) return;
  float g = bn[i], b = bn[C + i], m = bn[2 * C + i], v = bn[3 * C + i];
  float s = g / sqrtf(v + 1e-5f);
  sb[i] = s;
  sb[C + i] = b - m * s;
}

// ---------------- implicit-GEMM conv, 2D BEV tile + halo-staged A ----------------
// M-tile: 16(x) x 8(y) = 128 positions; halo strip 10x18 = 180 positions staged/kc.
// K-chunk = 64 ch; A/B LDS rows are 128B with XOR-8 16B-chunk swizzle
// (pre-swizzled GLOBAL source + swizzled ds_read; LDS writes stay linear).
// Out-of-image halo positions stage from zero page -> no read-side masking.
__global__ __launch_bounds__(256) void k_conv(
    const __hip_bfloat16* __restrict__ x0, const __hip_bfloat16* __restrict__ x1,
    int cin0, int cin1,
    const __hip_bfloat16* __restrict__ wp, const float* __restrict__ sb,
    int taps, int isFinal,
    __hip_bfloat16* __restrict__ obf, float* __restrict__ of32,
    const __hip_bfloat16* __restrict__ zp) {
  const int Cout = 384;
  __shared__ __hip_bfloat16 As[192 * 64];       // 24576 B  [pos s][64 ch]
  __shared__ __hip_bfloat16 Bs[2][128 * 64];    // 2 x 16384 B  [cout r][64 ch]
  const int t = threadIdx.x;
  const int w = t >> 6, l = t & 63;
  const int bid = blockIdx.x;
  const int b = bid / (XTILES * YTILES);
  const int rr = bid - b * (XTILES * YTILES);
  const int y0 = (rr / XTILES) * 8;
  const int x0c = (rr - (rr / XTILES) * XTILES) * 16;
  const int n0 = blockIdx.y * 128;
  const int cinTot = cin0 + cin1;
  const size_t tapStride = (size_t)Cout * cinTot * 2;  // bytes per tap in wp

  // ---- A staging precompute (6 issues x 256 threads = 1536 slots, 192 rows) ----
  int pA[6];
  bool okA[6];
  int cbA[6];
#pragma unroll
  for (int j = 0; j < 6; ++j) {
    int i = j * 256 + t;
    int s = i >> 3, c = i & 7;
    int yy = s / 18, xx = s - yy * 18;
    int ys = y0 - 1 + yy, xlin = x0c - 1 + xx;
    okA[j] = (s < 180) && ((unsigned)ys < 180u) && ((unsigned)xlin < 180u);
    pA[j] = b * NPOS + ys * BEV + xlin;
    cbA[j] = (c ^ (s & 7)) * 16;
  }
  // ---- B staging precompute (4 issues) ----
  size_t bOff[4];
#pragma unroll
  for (int j = 0; j < 4; ++j) {
    int i = j * 256 + t;
    int rB = i >> 3, c = i & 7;
    bOff[j] = (size_t)(n0 + rB) * cinTot * 2 + (size_t)((c ^ (rB & 7)) * 16);
  }

  f32x4 acc[4][4];
#pragma unroll
  for (int mi = 0; mi < 4; ++mi)
#pragma unroll
    for (int ni = 0; ni < 4; ++ni) acc[mi][ni] = f32x4{0.f, 0.f, 0.f, 0.f};

  const int wq = w >> 1;            // M half (0/1)
  const int wn = (w & 1) * 64;      // N quarter base
  const int xl = l & 15, kq = l >> 4;

  for (int seg = 0; seg < 2; ++seg) {
    const __hip_bfloat16* xs = seg ? x1 : x0;
    const int cin = seg ? cin1 : cin0;
    if (cin == 0) continue;
    const int segoff = seg ? cin0 : 0;
    const size_t cinB = (size_t)cin * 2;
    const char* aBase[6];
#pragma unroll
    for (int j = 0; j < 6; ++j)
      aBase[j] = okA[j] ? ((const char*)xs + (size_t)pA[j] * cinB + cbA[j]) : (const char*)zp;
    const int nkc = cin >> 6;
    for (int kc = 0; kc < nkc; ++kc) {
      // stage A halo strip (all taps share it)
#pragma unroll
      for (int j = 0; j < 6; ++j)
        gload_lds16(aBase[j] + (size_t)kc * 128, (char*)As + j * 4096 + w * 1024);
      // stage B tap0 -> buf0
      const char* wt0 = (const char*)wp + (size_t)(segoff + kc * 64) * 2;
#pragma unroll
      for (int j = 0; j < 4; ++j)
        gload_lds16(wt0 + bOff[j], (char*)Bs[0] + j * 4096 + w * 1024);
      asm volatile("s_waitcnt vmcnt(0)" ::: "memory");
      __syncthreads();
      for (int tap = 0; tap < taps; ++tap) {
        const int buf = tap & 1;
        if (tap + 1 < taps) {  // prefetch next tap's B into the other buffer
          const char* wt = (const char*)wp + (size_t)(tap + 1) * tapStride +
                           (size_t)(segoff + kc * 64) * 2;
#pragma unroll
          for (int j = 0; j < 4; ++j)
            gload_lds16(wt + bOff[j], (char*)Bs[buf ^ 1] + j * 4096 + w * 1024);
        }
        const int dy = (taps == 9) ? (tap / 3 - 1) : 0;
        const int dx = (taps == 9) ? (tap - (tap / 3) * 3 - 1) : 0;
        const int sBase = (wq * 4 + dy + 1) * 18 + xl + dx + 1;
#pragma unroll
        for (int ks = 0; ks < 2; ++ks) {
          const int g = ks * 4 + kq;
          bf16x8 af[4], bfr[4];
#pragma unroll
          for (int mi = 0; mi < 4; ++mi) {
            int s = sBase + mi * 18;
            af[mi] = *(const bf16x8*)((const char*)As + s * 128 + ((g ^ (s & 7)) * 16));
          }
#pragma unroll
          for (int ni = 0; ni < 4; ++ni) {
            int rB = wn + ni * 16 + xl;
            bfr[ni] = *(const bf16x8*)((const char*)Bs[buf] + rB * 128 + ((g ^ (rB & 7)) * 16));
          }
#pragma unroll
          for (int mi = 0; mi < 4; ++mi)
#pragma unroll
            for (int ni = 0; ni < 4; ++ni)
              acc[mi][ni] = __builtin_amdgcn_mfma_f32_16x16x32_bf16(af[mi], bfr[ni], acc[mi][ni], 0, 0, 0);
        }
        asm volatile("s_waitcnt vmcnt(0)" ::: "memory");  // next-tap B landed
        __syncthreads();                                  // all reads of old buf done
      }
    }
  }

  // ---- epilogue: BN + ReLU, store ----
  float sc[4], bi[4];
#pragma unroll
  for (int ni = 0; ni < 4; ++ni) {
    int cc = n0 + wn + ni * 16 + xl;
    sc[ni] = sb[cc];
    bi[ni] = sb[Cout + cc];
  }
#pragma unroll
  for (int mi = 0; mi < 4; ++mi) {
    int yl = wq * 4 + mi;
    int y = y0 + yl;
#pragma unroll
    for (int j = 0; j < 4; ++j) {
      int xr = kq * 4 + j;  // C/D layout: row = (lane>>4)*4 + j
      int x = x0c + xr;
      if (y >= BEV || x >= BEV) continue;
      int p = b * NPOS + y * BEV + x;
#pragma unroll
      for (int ni = 0; ni < 4; ++ni) {
        int cc = n0 + wn + ni * 16 + xl;
        float v = fmaxf(acc[mi][ni][j] * sc[ni] + bi[ni], 0.f);
        if (isFinal) {
          of32[((size_t)(b * Cout + cc)) * NPOS + (size_t)y * BEV + x] = v;
        } else {
          obf[(size_t)p * Cout + cc] = __float2bfloat16(v);
        }
      }
    }
  }
}

extern "C" void kernel_launch(void* const* d_in, const int* in_sizes, int n_in,
                              void* d_out, int out_size, void* d_ws, size_t ws_size,
                              hipStream_t stream) {
  const float* radar = (const float*)d_in[0];
  const float* imgf = (const float*)d_in[1];
  const float* l2i = (const float*)d_in[2];
  const float* w1 = (const float*)d_in[3];
  const float* bn1 = (const float*)d_in[4];
  const float* w2 = (const float*)d_in[5];
  const float* bn2 = (const float*)d_in[6];
  const float* wf1 = (const float*)d_in[7];
  const float* bnf1 = (const float*)d_in[8];
  const float* wf2 = (const float*)d_in[9];
  const float* bnf2 = (const float*)d_in[10];

  char* ws = (char*)d_ws;
  size_t off = 0;
  auto alloc = [&](size_t bytes) {
    char* p = ws + off;
    off += (bytes + 255) & ~(size_t)255;
    return p;
  };
  char* zp = alloc(4096);
  char* imgT = alloc((size_t)2 * IH * IW * CIMG * 4);   // 23.0 MB fp32 NHWC
  char* ibev = alloc((size_t)MTOT * CIMG * 2);          // 33.2 MB bf16 NHWC
  char* radarT = imgT;                                  // alias: used after imgT/ibev dead
  char* h1 = alloc((size_t)MTOT * 384 * 2);             // 49.8 MB
  char* h2 = alloc((size_t)MTOT * 384 * 2);             // 49.8 MB
  char* f1 = h1;                                        // alias: h1 dead after conv2
  char* wp1 = alloc((size_t)1 * 384 * 256 * 2);
  char* wp2 = alloc((size_t)9 * 384 * 384 * 2);
  char* wpf1 = alloc((size_t)9 * 384 * 768 * 2);
  char* wpf2 = alloc((size_t)9 * 384 * 384 * 2);
  char* sb1 = alloc(2 * 384 * 4);
  char* sb2 = alloc(2 * 384 * 4);
  char* sbf1 = alloc(2 * 384 * 4);
  char* sbf2 = alloc(2 * 384 * 4);

  k_zero<<<1, 512, 0, stream>>>((unsigned long long*)zp);

  dim3 tb(32, 8);
  // img_feat NCHW -> NHWC fp32
  k_transpose<float><<<dim3((IH * IW + 31) / 32, (CIMG + 31) / 32, 2), tb, 0, stream>>>(
      imgf, (float*)imgT, CIMG, IH * IW);

  auto packw = [&](const float* src, char* dst, int Co, int Ci, int T) {
    size_t tot = (size_t)Co * Ci * T;
    k_packw<<<(unsigned)((tot + 255) / 256), 256, 0, stream>>>(src, (__hip_bfloat16*)dst, Co, Ci, T);
  };
  packw(w1, wp1, 384, 256, 1);
  packw(w2, wp2, 384, 384, 9);
  packw(wf1, wpf1, 384, 768, 9);
  packw(wf2, wpf2, 384, 384, 9);
  k_packbn<<<2, 256, 0, stream>>>(bn1, (float*)sb1, 384);
  k_packbn<<<2, 256, 0, stream>>>(bn2, (float*)sb2, 384);
  k_packbn<<<2, 256, 0, stream>>>(bnf1, (float*)sbf1, 384);
  k_packbn<<<2, 256, 0, stream>>>(bnf2, (float*)sbf2, 384);

  // sampling -> image_bev NHWC bf16
  k_sample<<<MTOT, 256, 0, stream>>>((const float*)imgT, l2i, (__hip_bfloat16*)ibev);

  dim3 cg(MBLK, 3);
  // conv1: 1x1, image_bev(256) -> h1(384)
  k_conv<<<cg, 256, 0, stream>>>((const __hip_bfloat16*)ibev, nullptr, 256, 0,
                                 (const __hip_bfloat16*)wp1, (const float*)sb1, 1, 0,
                                 (__hip_bfloat16*)h1, nullptr, (const __hip_bfloat16*)zp);
  // radar NCHW -> NHWC bf16 (aliases imgT/ibev — both dead after conv1)
  k_transpose<__hip_bfloat16><<<dim3((NPOS + 31) / 32, (384 + 31) / 32, 2), tb, 0, stream>>>(
      radar, (__hip_bfloat16*)radarT, 384, NPOS);
  // conv2: 3x3, h1(384) -> h2(384)
  k_conv<<<cg, 256, 0, stream>>>((const __hip_bfloat16*)h1, nullptr, 384, 0,
                                 (const __hip_bfloat16*)wp2, (const float*)sb2, 9, 0,
                                 (__hip_bfloat16*)h2, nullptr, (const __hip_bfloat16*)zp);
  // convf1: 3x3, concat(radar, h2)(768) -> f1(384)
  k_conv<<<cg, 256, 0, stream>>>((const __hip_bfloat16*)radarT, (const __hip_bfloat16*)h2, 384, 384,
                                 (const __hip_bfloat16*)wpf1, (const float*)sbf1, 9, 0,
                                 (__hip_bfloat16*)f1, nullptr, (const __hip_bfloat16*)zp);
  // convf2: 3x3, f1(384) -> d_out fp32 NCHW
  k_conv<<<cg, 256, 0, stream>>>((const __hip_bfloat16*)f1, nullptr, 384, 0,
                                 (const __hip_bfloat16*)wpf2, (const float*)sbf2, 9, 1,
                                 nullptr, (float*)d_out, (const __hip_bfloat16*)zp);
}

// Round 5
// 1159.273 us; speedup vs baseline: 1.0145x; 1.0145x over previous
//
#include <hip/hip_runtime.h>
#include <hip/hip_bf16.h>

#define BEV 180
#define NPOS (BEV * BEV)   // 32400
#define MTOT (2 * NPOS)    // 64800
#define IH 64
#define IW 176
#define CIMG 256
#define XTILES 12          // 12*16 = 192 >= 180
#define YTILES 23          // 23*8  = 184 >= 180
#define MBLK (XTILES * YTILES * 2)  // 552

typedef __attribute__((ext_vector_type(8))) short bf16x8;
typedef __attribute__((ext_vector_type(4))) float f32x4;

__device__ __forceinline__ void gload_lds16(const void* g, void* l) {
  __builtin_amdgcn_global_load_lds(
      (const __attribute__((address_space(1))) void*)g,
      (__attribute__((address_space(3))) void*)l, 16, 0, 0);
}

// ---------------- zero page ----------------
__global__ void k_zero(unsigned long long* p) { p[threadIdx.x] = 0ULL; }

// ---------------- generic fp32 [B][R][CL] -> [B][CL][R] transpose ----------------
template <typename OT>
__device__ __forceinline__ OT conv_out(float v);
template <>
__device__ __forceinline__ float conv_out<float>(float v) { return v; }
template <>
__device__ __forceinline__ __hip_bfloat16 conv_out<__hip_bfloat16>(float v) { return __float2bfloat16(v); }

template <typename OT>
__global__ void k_transpose(const float* __restrict__ in, OT* __restrict__ out, int R, int CL) {
  __shared__ float tile[32][33];
  const float* inb = in + (size_t)blockIdx.z * R * CL;
  OT* outb = out + (size_t)blockIdx.z * R * CL;
  int c0 = blockIdx.x * 32, r0 = blockIdx.y * 32;
  int tx = threadIdx.x, ty = threadIdx.y;
#pragma unroll
  for (int i = 0; i < 32; i += 8) {
    int r = r0 + ty + i, c = c0 + tx;
    tile[ty + i][tx] = (r < R && c < CL) ? inb[(size_t)r * CL + c] : 0.f;
  }
  __syncthreads();
#pragma unroll
  for (int i = 0; i < 32; i += 8) {
    int c = c0 + ty + i, r = r0 + tx;
    if (c < CL && r < R) outb[(size_t)c * R + r] = conv_out<OT>(tile[tx][ty + i]);
  }
}

// ---------------- projection + bilinear sample -> image_bev NHWC bf16 ----------------
__global__ void k_sample(const float* __restrict__ imgT, const float* __restrict__ l2i,
                         __hip_bfloat16* __restrict__ out) {
  int blk = blockIdx.x;
  int b = blk / NPOS, rem = blk - b * NPOS;
  int hy = rem / BEV, wx = rem - hy * BEV;
  int c = threadIdx.x;
  float gx = -54.f + 0.3f + 0.6f * (float)wx;
  float gy = -54.f + 0.3f + 0.6f * (float)hy;
  const float* L = l2i + b * 12;
  const float* img = imgT + (size_t)b * (IH * IW * CIMG);
  float acc = 0.f, vcnt = 0.f;
#pragma unroll
  for (int zi = 0; zi < 3; ++zi) {
    float z = (float)(zi - 1);
    float p0 = L[0] * gx + L[1] * gy + L[2] * z + L[3];
    float p1 = L[4] * gx + L[5] * gy + L[6] * z + L[7];
    float p2 = L[8] * gx + L[9] * gy + L[10] * z + L[11];
    float d = fmaxf(p2, 1e-5f);
    float px = p0 / d, py = p1 / d;
    if (px >= 0.f && px < 704.f && py >= 0.f && py < 256.f && p2 > 1e-5f) {
      vcnt += 1.f;
      float ix = px * 0.25f - 0.5f, iy = py * 0.25f - 0.5f;
      float xf = floorf(ix), yf = floorf(iy);
      float wx1 = ix - xf, wy1 = iy - yf;
      float wx0 = 1.f - wx1, wy0 = 1.f - wy1;
      int x0 = (int)xf, y0 = (int)yf;
      int x1 = x0 + 1, y1 = y0 + 1;
      bool bx0 = (unsigned)x0 < IW, bx1 = (unsigned)x1 < IW;
      bool by0 = (unsigned)y0 < IH, by1 = (unsigned)y1 < IH;
      float s = 0.f;
      if (bx0 && by0) s += wx0 * wy0 * img[((size_t)y0 * IW + x0) * CIMG + c];
      if (bx1 && by0) s += wx1 * wy0 * img[((size_t)y0 * IW + x1) * CIMG + c];
      if (bx0 && by1) s += wx0 * wy1 * img[((size_t)y1 * IW + x0) * CIMG + c];
      if (bx1 && by1) s += wx1 * wy1 * img[((size_t)y1 * IW + x1) * CIMG + c];
      acc += s;
    }
  }
  out[(size_t)blk * CIMG + c] = __float2bfloat16(acc / fmaxf(vcnt, 1.f));
}

// ---------------- weight pack: w[co][ci][tap] fp32 -> wp[tap][co][ci] bf16 ----------------
__global__ void k_packw(const float* __restrict__ w, __hip_bfloat16* __restrict__ wp,
                        int Co, int Ci, int T) {
  size_t idx = (size_t)blockIdx.x * 256 + threadIdx.x;
  size_t tot = (size_t)Co * Ci * T;
  if (idx >= tot) return;
  int ci = (int)(idx % Ci);
  size_t r = idx / Ci;
  int co = (int)(r % Co);
  int tap = (int)(r / Co);
  wp[idx] = __float2bfloat16(w[((size_t)co * Ci + ci) * T + tap]);
}

// ---------------- BN fold: [4][C] -> [2][C] (scale, bias) ----------------
__global__ void k_packbn(const float* __restrict__ bn, float* __restrict__ sb, int C) {
  int i = blockIdx.x * blockDim.x + threadIdx.x;
  if (i >= C) return;
  float g = bn[i], b = bn[C + i], m = bn[2 * C + i], v = bn[3 * C + i];
  float s = g / sqrtf(v + 1e-5f);
  sb[i] = s;
  sb[C + i] = b - m * s;
}

// ---------------- implicit-GEMM conv, phase-pipelined (T3+T4+T5) ----------------
// Flattened phases p = (seg,kc) x tap. Per phase: issue B(p+1) [4 loads/thread,
// double-buffered], at tap0 issue A(kc+1) [6 loads, double-buffered, 9-phase
// lead], counted s_waitcnt vmcnt (never 0 mid-loop), raw s_barrier, setprio'd
// 32-MFMA cluster, raw s_barrier. LDS = 48K A + 32K B = 80K -> 2 blocks/CU.
__global__ __launch_bounds__(256) void k_conv(
    const __hip_bfloat16* __restrict__ x0, const __hip_bfloat16* __restrict__ x1,
    int cin0, int cin1,
    const __hip_bfloat16* __restrict__ wp, const float* __restrict__ sb,
    int taps, int isFinal,
    __hip_bfloat16* __restrict__ obf, float* __restrict__ of32,
    const __hip_bfloat16* __restrict__ zp) {
  const int Cout = 384;
  __shared__ __hip_bfloat16 As[2][192 * 64];    // 2 x 24576 B  [pos s][64 ch]
  __shared__ __hip_bfloat16 Bs[2][128 * 64];    // 2 x 16384 B  [cout r][64 ch]
  const int t = threadIdx.x;
  const int w = t >> 6, l = t & 63;
  const int bid = blockIdx.x;
  const int b = bid / (XTILES * YTILES);
  const int rr = bid - b * (XTILES * YTILES);
  const int y0 = (rr / XTILES) * 8;
  const int x0c = (rr - (rr / XTILES) * XTILES) * 16;
  const int n0 = blockIdx.y * 128;
  const int cinTot = cin0 + cin1;
  const size_t tapStride = (size_t)Cout * cinTot * 2;  // bytes per tap in wp
  const int nA0 = cin0 >> 6, nA1 = cin1 >> 6, nA = nA0 + nA1;
  const int P = nA * taps;

  // ---- A staging precompute (6 issues x 256 threads, 192 rows of 128B) ----
  const char* aB0[6];
  const char* aB1[6];
#pragma unroll
  for (int j = 0; j < 6; ++j) {
    int i = j * 256 + t;
    int s = i >> 3, c = i & 7;
    int yy = s / 18, xx = s - yy * 18;
    int ys = y0 - 1 + yy, xlin = x0c - 1 + xx;
    bool ok = (s < 180) && ((unsigned)ys < 180u) && ((unsigned)xlin < 180u);
    size_t pos = (size_t)(b * NPOS + ys * BEV + xlin);
    size_t cb = (size_t)((c ^ (s & 7)) * 16);
    aB0[j] = ok ? ((const char*)x0 + pos * (size_t)(cin0 * 2) + cb) : (const char*)zp;
    aB1[j] = (ok && cin1) ? ((const char*)x1 + pos * (size_t)(cin1 * 2) + cb) : (const char*)zp;
  }
  // ---- B staging precompute (4 issues) ----
  size_t bOff[4];
#pragma unroll
  for (int j = 0; j < 4; ++j) {
    int i = j * 256 + t;
    int rB = i >> 3, c = i & 7;
    bOff[j] = (size_t)(n0 + rB) * cinTot * 2 + (size_t)((c ^ (rB & 7)) * 16);
  }

  // issue helpers
  auto issueA = [&](int a) {  // stage A chunk a -> As[a&1]
    int s1 = (a >= nA0);
    int kcw = a - (s1 ? nA0 : 0);
    char* dst = (char*)As[a & 1] + w * 1024;
#pragma unroll
    for (int j = 0; j < 6; ++j) {
      const char* src = (s1 ? aB1[j] : aB0[j]);
      gload_lds16(src == (const char*)zp ? src : src + (size_t)kcw * 128, dst + j * 4096);
    }
  };
  auto issueB = [&](int q, int aq, int tq) {  // stage B for phase q -> Bs[q&1]
    int s1 = (aq >= nA0);
    int kcw = aq - (s1 ? nA0 : 0);
    int segoff = s1 ? cin0 : 0;
    const char* wt = (const char*)wp + (size_t)tq * tapStride + (size_t)(segoff + kcw * 64) * 2;
    char* dst = (char*)Bs[q & 1] + w * 1024;
#pragma unroll
    for (int j = 0; j < 4; ++j) gload_lds16(wt + bOff[j], dst + j * 4096);
  };

  f32x4 acc[4][4];
#pragma unroll
  for (int mi = 0; mi < 4; ++mi)
#pragma unroll
    for (int ni = 0; ni < 4; ++ni) acc[mi][ni] = f32x4{0.f, 0.f, 0.f, 0.f};

  const int wq = w >> 1;            // M half (0/1)
  const int wn = (w & 1) * 64;      // N quarter base
  const int xl = l & 15, kq = l >> 4;

  // ---- prologue: stage phase 0 ----
  issueB(0, 0, 0);
  issueA(0);

  int a = 0, tap = 0;
  for (int p = 0; p < P; ++p) {
    // issue next-phase B (target Bs[(p+1)&1], last read at phase p-1)
    if (p + 1 < P) {
      int tq = tap + 1, aq = a;
      if (tq == taps) { tq = 0; ++aq; }
      issueB(p + 1, aq, tq);
    }
    // issue next A chunk at tap0 (target As[(a+1)&1], last read in kc a-1)
    if (tap == 0 && a + 1 < nA) issueA(a + 1);

    // counted wait: drain everything older than this phase's not-yet-needed
    // issues. K = 4*(B(p+1) issued) + 6*(A(a+1) in flight, issued this or prev phase)
    {
      int K = ((p + 1 < P) ? 4 : 0) + ((tap <= 1 && a + 1 < nA) ? 6 : 0);
      if (K == 10)      asm volatile("s_waitcnt vmcnt(10)" ::: "memory");
      else if (K == 6)  asm volatile("s_waitcnt vmcnt(6)" ::: "memory");
      else if (K == 4)  asm volatile("s_waitcnt vmcnt(4)" ::: "memory");
      else              asm volatile("s_waitcnt vmcnt(0)" ::: "memory");
    }
    __builtin_amdgcn_s_barrier();     // b1: phase-p data visible to all waves
    asm volatile("" ::: "memory");

    const int dy = (taps == 9) ? (tap / 3 - 1) : 0;
    const int dx = (taps == 9) ? (tap - (tap / 3) * 3 - 1) : 0;
    const int sBase = (wq * 4 + dy + 1) * 18 + xl + dx + 1;
    const char* aLds = (const char*)As[a & 1];
    const char* bLds = (const char*)Bs[p & 1];
    __builtin_amdgcn_s_setprio(1);
#pragma unroll
    for (int ks = 0; ks < 2; ++ks) {
      const int g = ks * 4 + kq;
      bf16x8 af[4], bfr[4];
#pragma unroll
      for (int mi = 0; mi < 4; ++mi) {
        int s = sBase + mi * 18;
        af[mi] = *(const bf16x8*)(aLds + s * 128 + ((g ^ (s & 7)) * 16));
      }
#pragma unroll
      for (int ni = 0; ni < 4; ++ni) {
        int rB = wn + ni * 16 + xl;
        bfr[ni] = *(const bf16x8*)(bLds + rB * 128 + ((g ^ (rB & 7)) * 16));
      }
#pragma unroll
      for (int mi = 0; mi < 4; ++mi)
#pragma unroll
        for (int ni = 0; ni < 4; ++ni)
          acc[mi][ni] = __builtin_amdgcn_mfma_f32_16x16x32_bf16(af[mi], bfr[ni], acc[mi][ni], 0, 0, 0);
    }
    __builtin_amdgcn_s_setprio(0);
    asm volatile("" ::: "memory");
    __builtin_amdgcn_s_barrier();     // b2: all reads of phase-p buffers done

    if (++tap == taps) { tap = 0; ++a; }
  }

  // ---- epilogue: BN + ReLU, store ----
  float sc[4], bi[4];
#pragma unroll
  for (int ni = 0; ni < 4; ++ni) {
    int cc = n0 + wn + ni * 16 + xl;
    sc[ni] = sb[cc];
    bi[ni] = sb[Cout + cc];
  }
#pragma unroll
  for (int mi = 0; mi < 4; ++mi) {
    int yl = wq * 4 + mi;
    int y = y0 + yl;
#pragma unroll
    for (int j = 0; j < 4; ++j) {
      int xr = kq * 4 + j;  // C/D layout: row = (lane>>4)*4 + j
      int x = x0c + xr;
      if (y >= BEV || x >= BEV) continue;
      int p = b * NPOS + y * BEV + x;
#pragma unroll
      for (int ni = 0; ni < 4; ++ni) {
        int cc = n0 + wn + ni * 16 + xl;
        float v = fmaxf(acc[mi][ni][j] * sc[ni] + bi[ni], 0.f);
        if (isFinal) {
          of32[((size_t)(b * Cout + cc)) * NPOS + (size_t)y * BEV + x] = v;
        } else {
          obf[(size_t)p * Cout + cc] = __float2bfloat16(v);
        }
      }
    }
  }
}

extern "C" void kernel_launch(void* const* d_in, const int* in_sizes, int n_in,
                              void* d_out, int out_size, void* d_ws, size_t ws_size,
                              hipStream_t stream) {
  const float* radar = (const float*)d_in[0];
  const float* imgf = (const float*)d_in[1];
  const float* l2i = (const float*)d_in[2];
  const float* w1 = (const float*)d_in[3];
  const float* bn1 = (const float*)d_in[4];
  const float* w2 = (const float*)d_in[5];
  const float* bn2 = (const float*)d_in[6];
  const float* wf1 = (const float*)d_in[7];
  const float* bnf1 = (const float*)d_in[8];
  const float* wf2 = (const float*)d_in[9];
  const float* bnf2 = (const float*)d_in[10];

  char* ws = (char*)d_ws;
  size_t off = 0;
  auto alloc = [&](size_t bytes) {
    char* p = ws + off;
    off += (bytes + 255) & ~(size_t)255;
    return p;
  };
  char* zp = alloc(4096);
  char* imgT = alloc((size_t)2 * IH * IW * CIMG * 4);   // 23.0 MB fp32 NHWC
  char* ibev = alloc((size_t)MTOT * CIMG * 2);          // 33.2 MB bf16 NHWC
  char* radarT = imgT;                                  // alias: used after imgT/ibev dead
  char* h1 = alloc((size_t)MTOT * 384 * 2);             // 49.8 MB
  char* h2 = alloc((size_t)MTOT * 384 * 2);             // 49.8 MB
  char* f1 = h1;                                        // alias: h1 dead after conv2
  char* wp1 = alloc((size_t)1 * 384 * 256 * 2);
  char* wp2 = alloc((size_t)9 * 384 * 384 * 2);
  char* wpf1 = alloc((size_t)9 * 384 * 768 * 2);
  char* wpf2 = alloc((size_t)9 * 384 * 384 * 2);
  char* sb1 = alloc(2 * 384 * 4);
  char* sb2 = alloc(2 * 384 * 4);
  char* sbf1 = alloc(2 * 384 * 4);
  char* sbf2 = alloc(2 * 384 * 4);

  k_zero<<<1, 512, 0, stream>>>((unsigned long long*)zp);

  dim3 tb(32, 8);
  // img_feat NCHW -> NHWC fp32
  k_transpose<float><<<dim3((IH * IW + 31) / 32, (CIMG + 31) / 32, 2), tb, 0, stream>>>(
      imgf, (float*)imgT, CIMG, IH * IW);

  auto packw = [&](const float* src, char* dst, int Co, int Ci, int T) {
    size_t tot = (size_t)Co * Ci * T;
    k_packw<<<(unsigned)((tot + 255) / 256), 256, 0, stream>>>(src, (__hip_bfloat16*)dst, Co, Ci, T);
  };
  packw(w1, wp1, 384, 256, 1);
  packw(w2, wp2, 384, 384, 9);
  packw(wf1, wpf1, 384, 768, 9);
  packw(wf2, wpf2, 384, 384, 9);
  k_packbn<<<2, 256, 0, stream>>>(bn1, (float*)sb1, 384);
  k_packbn<<<2, 256, 0, stream>>>(bn2, (float*)sb2, 384);
  k_packbn<<<2, 256, 0, stream>>>(bnf1, (float*)sbf1, 384);
  k_packbn<<<2, 256, 0, stream>>>(bnf2, (float*)sbf2, 384);

  // sampling -> image_bev NHWC bf16
  k_sample<<<MTOT, 256, 0, stream>>>((const float*)imgT, l2i, (__hip_bfloat16*)ibev);

  dim3 cg(MBLK, 3);
  // conv1: 1x1, image_bev(256) -> h1(384)
  k_conv<<<cg, 256, 0, stream>>>((const __hip_bfloat16*)ibev, nullptr, 256, 0,
                                 (const __hip_bfloat16*)wp1, (const float*)sb1, 1, 0,
                                 (__hip_bfloat16*)h1, nullptr, (const __hip_bfloat16*)zp);
  // radar NCHW -> NHWC bf16 (aliases imgT/ibev — both dead after conv1)
  k_transpose<__hip_bfloat16><<<dim3((NPOS + 31) / 32, (384 + 31) / 32, 2), tb, 0, stream>>>(
      radar, (__hip_bfloat16*)radarT, 384, NPOS);
  // conv2: 3x3, h1(384) -> h2(384)
  k_conv<<<cg, 256, 0, stream>>>((const __hip_bfloat16*)h1, nullptr, 384, 0,
                                 (const __hip_bfloat16*)wp2, (const float*)sb2, 9, 0,
                                 (__hip_bfloat16*)h2, nullptr, (const __hip_bfloat16*)zp);
  // convf1: 3x3, concat(radar, h2)(768) -> f1(384)
  k_conv<<<cg, 256, 0, stream>>>((const __hip_bfloat16*)radarT, (const __hip_bfloat16*)h2, 384, 384,
                                 (const __hip_bfloat16*)wpf1, (const float*)sbf1, 9, 0,
                                 (__hip_bfloat16*)f1, nullptr, (const __hip_bfloat16*)zp);
  // convf2: 3x3, f1(384) -> d_out fp32 NCHW
  k_conv<<<cg, 256, 0, stream>>>((const __hip_bfloat16*)f1, nullptr, 384, 0,
                                 (const __hip_bfloat16*)wpf2, (const float*)sbf2, 9, 1,
                                 nullptr, (float*)d_out, (const __hip_bfloat16*)zp);
}

// Round 6
// 940.041 us; speedup vs baseline: 1.2511x; 1.2332x over previous
//
#include <hip/hip_runtime.h>
#include <hip/hip_bf16.h>

#define BEV 180
#define NPOS (BEV * BEV)   // 32400
#define MTOT (2 * NPOS)    // 64800
#define IH 64
#define IW 176
#define CIMG 256

typedef __attribute__((ext_vector_type(8))) short bf16x8;
typedef __attribute__((ext_vector_type(4))) float f32x4;

__device__ __forceinline__ void gload_lds16(const void* g, void* l) {
  __builtin_amdgcn_global_load_lds(
      (const __attribute__((address_space(1))) void*)g,
      (__attribute__((address_space(3))) void*)l, 16, 0, 0);
}

// ---------------- zero page ----------------
__global__ void k_zero(unsigned long long* p) { p[threadIdx.x] = 0ULL; }

// ---------------- generic fp32 [B][R][CL] -> [B][CL][R] transpose ----------------
template <typename OT>
__device__ __forceinline__ OT conv_out(float v);
template <>
__device__ __forceinline__ float conv_out<float>(float v) { return v; }
template <>
__device__ __forceinline__ __hip_bfloat16 conv_out<__hip_bfloat16>(float v) { return __float2bfloat16(v); }

template <typename OT>
__global__ void k_transpose(const float* __restrict__ in, OT* __restrict__ out, int R, int CL) {
  __shared__ float tile[32][33];
  const float* inb = in + (size_t)blockIdx.z * R * CL;
  OT* outb = out + (size_t)blockIdx.z * R * CL;
  int c0 = blockIdx.x * 32, r0 = blockIdx.y * 32;
  int tx = threadIdx.x, ty = threadIdx.y;
#pragma unroll
  for (int i = 0; i < 32; i += 8) {
    int r = r0 + ty + i, c = c0 + tx;
    tile[ty + i][tx] = (r < R && c < CL) ? inb[(size_t)r * CL + c] : 0.f;
  }
  __syncthreads();
#pragma unroll
  for (int i = 0; i < 32; i += 8) {
    int c = c0 + ty + i, r = r0 + tx;
    if (c < CL && r < R) outb[(size_t)c * R + r] = conv_out<OT>(tile[tx][ty + i]);
  }
}

// ---------------- projection + bilinear sample -> image_bev NHWC bf16 ----------------
__global__ void k_sample(const float* __restrict__ imgT, const float* __restrict__ l2i,
                         __hip_bfloat16* __restrict__ out) {
  int blk = blockIdx.x;
  int b = blk / NPOS, rem = blk - b * NPOS;
  int hy = rem / BEV, wx = rem - hy * BEV;
  int c = threadIdx.x;
  float gx = -54.f + 0.3f + 0.6f * (float)wx;
  float gy = -54.f + 0.3f + 0.6f * (float)hy;
  const float* L = l2i + b * 12;
  const float* img = imgT + (size_t)b * (IH * IW * CIMG);
  float acc = 0.f, vcnt = 0.f;
#pragma unroll
  for (int zi = 0; zi < 3; ++zi) {
    float z = (float)(zi - 1);
    float p0 = L[0] * gx + L[1] * gy + L[2] * z + L[3];
    float p1 = L[4] * gx + L[5] * gy + L[6] * z + L[7];
    float p2 = L[8] * gx + L[9] * gy + L[10] * z + L[11];
    float d = fmaxf(p2, 1e-5f);
    float px = p0 / d, py = p1 / d;
    if (px >= 0.f && px < 704.f && py >= 0.f && py < 256.f && p2 > 1e-5f) {
      vcnt += 1.f;
      float ix = px * 0.25f - 0.5f, iy = py * 0.25f - 0.5f;
      float xf = floorf(ix), yf = floorf(iy);
      float wx1 = ix - xf, wy1 = iy - yf;
      float wx0 = 1.f - wx1, wy0 = 1.f - wy1;
      int x0 = (int)xf, y0 = (int)yf;
      int x1 = x0 + 1, y1 = y0 + 1;
      bool bx0 = (unsigned)x0 < IW, bx1 = (unsigned)x1 < IW;
      bool by0 = (unsigned)y0 < IH, by1 = (unsigned)y1 < IH;
      float s = 0.f;
      if (bx0 && by0) s += wx0 * wy0 * img[((size_t)y0 * IW + x0) * CIMG + c];
      if (bx1 && by0) s += wx1 * wy0 * img[((size_t)y0 * IW + x1) * CIMG + c];
      if (bx0 && by1) s += wx0 * wy1 * img[((size_t)y1 * IW + x0) * CIMG + c];
      if (bx1 && by1) s += wx1 * wy1 * img[((size_t)y1 * IW + x1) * CIMG + c];
      acc += s;
    }
  }
  out[(size_t)blk * CIMG + c] = __float2bfloat16(acc / fmaxf(vcnt, 1.f));
}

// ---------------- weight pack: w[co][ci][tap] fp32 -> wp[tap][co][ci] bf16 ----------------
__global__ void k_packw(const float* __restrict__ w, __hip_bfloat16* __restrict__ wp,
                        int Co, int Ci, int T) {
  size_t idx = (size_t)blockIdx.x * 256 + threadIdx.x;
  size_t tot = (size_t)Co * Ci * T;
  if (idx >= tot) return;
  int ci = (int)(idx % Ci);
  size_t r = idx / Ci;
  int co = (int)(r % Co);
  int tap = (int)(r / Co);
  wp[idx] = __float2bfloat16(w[((size_t)co * Ci + ci) * T + tap]);
}

// ---------------- BN fold: [4][C] -> [2][C] (scale, bias) ----------------
__global__ void k_packbn(const float* __restrict__ bn, float* __restrict__ sb, int C) {
  int i = blockIdx.x * blockDim.x + threadIdx.x;
  if (i >= C) return;
  float g = bn[i], b = bn[C + i], m = bn[2 * C + i], v = bn[3 * C + i];
  float s = g / sqrtf(v + 1e-5f);
  sb[i] = s;
  sb[C + i] = b - m * s;
}

// ---------------- implicit-GEMM conv: 256x128 block, 128x64 wave tile ----------------
// M-tile: 16x x 16y = 256 positions; halo 18x18 = 324 rows (staged as 352, 11 issues).
// 4 waves (2M x 2N), wave tile 128(M) x 64(N): per phase 24 ds_read_b128 + 64 MFMA.
// A single-buffered (changes once per 9 taps; re-issued after the kc's last barrier);
// B double-buffered 1 phase ahead; counted vmcnt(4) mid-loop; setprio'd MFMA cluster.
// LDS = 45056(A) + 32768(B) = 77824 B -> 2 blocks/CU.
__global__ __launch_bounds__(256, 2) void k_conv(
    const __hip_bfloat16* __restrict__ x0, const __hip_bfloat16* __restrict__ x1,
    int cin0, int cin1,
    const __hip_bfloat16* __restrict__ wp, const float* __restrict__ sb,
    int taps, int isFinal,
    __hip_bfloat16* __restrict__ obf, float* __restrict__ of32,
    const __hip_bfloat16* __restrict__ zp) {
  const int Cout = 384;
  __shared__ __hip_bfloat16 As[352 * 64];       // 45056 B  [halo row s][64 ch]
  __shared__ __hip_bfloat16 Bs[2][128 * 64];    // 2 x 16384 B  [cout r][64 ch]
  const int t = threadIdx.x;
  const int w = t >> 6, l = t & 63;
  const int bid = blockIdx.x;
  const int b = bid / 144;
  const int rr = bid - b * 144;
  const int y0 = (rr / 12) * 16;
  const int x0c = (rr - (rr / 12) * 12) * 16;
  const int n0 = blockIdx.y * 128;
  const int cinTot = cin0 + cin1;
  const size_t tapStride = (size_t)Cout * cinTot * 2;  // bytes per tap in wp
  const int nA0 = cin0 >> 6, nA1 = cin1 >> 6, nA = nA0 + nA1;
  const int P = nA * taps;

  // ---- A staging precompute: 11 issues x 256 threads -> 352 rows of 128 B ----
  const int baseRow = t >> 3;
  const int cb = ((t & 7) ^ (baseRow & 7)) * 16;   // XOR-8 pre-swizzle (row&7 == baseRow&7)
  int posIdx[11];
  unsigned okMask = 0;
#pragma unroll
  for (int j = 0; j < 11; ++j) {
    int row = j * 32 + baseRow;
    int yy = row / 18, xx = row - yy * 18;
    int ys = y0 - 1 + yy, xg = x0c - 1 + xx;
    if (row < 324 && (unsigned)ys < 180u && (unsigned)xg < 180u) okMask |= (1u << j);
    posIdx[j] = b * NPOS + ys * BEV + xg;
  }
  // ---- B staging precompute (4 issues) ----
  size_t bOff[4];
#pragma unroll
  for (int j = 0; j < 4; ++j)
    bOff[j] = (size_t)(n0 + j * 32 + baseRow) * (size_t)(cinTot * 2) + (size_t)cb;

  auto issueA = [&](int kc) {  // stage A chunk kc into the single A buffer
    int s1 = (kc >= nA0);
    int kcw = kc - (s1 ? nA0 : 0);
    const char* xb = s1 ? (const char*)x1 : (const char*)x0;
    size_t cinB = (size_t)(s1 ? cin1 : cin0) * 2;
    size_t ko = (size_t)kcw * 128 + (size_t)cb;
    char* dst = (char*)As + w * 1024;
#pragma unroll
    for (int j = 0; j < 11; ++j) {
      const char* src = ((okMask >> j) & 1) ? (xb + (size_t)posIdx[j] * cinB + ko)
                                            : (const char*)zp;
      gload_lds16(src, dst + j * 4096);
    }
  };
  auto issueB = [&](int q, int kc, int tq) {  // stage B for phase q -> Bs[q&1]
    int s1 = (kc >= nA0);
    int kcw = kc - (s1 ? nA0 : 0);
    int segoff = s1 ? cin0 : 0;
    const char* wt = (const char*)wp + (size_t)tq * tapStride + (size_t)(segoff + kcw * 64) * 2;
    char* dst = (char*)Bs[q & 1] + w * 1024;
#pragma unroll
    for (int j = 0; j < 4; ++j) gload_lds16(wt + bOff[j], dst + j * 4096);
  };

  f32x4 acc[8][4];
#pragma unroll
  for (int mi = 0; mi < 8; ++mi)
#pragma unroll
    for (int ni = 0; ni < 4; ++ni) acc[mi][ni] = f32x4{0.f, 0.f, 0.f, 0.f};

  const int wq = w >> 1;            // M half: y-rows [wq*8, wq*8+8)
  const int wn = (w & 1) * 64;      // N half base
  const int xl = l & 15, kq = l >> 4;

  // ---- prologue ----
  issueA(0);
  issueB(0, 0, 0);

  int kc = 0, tap = 0;
  for (int p = 0; p < P; ++p) {
    if (p + 1 < P) {
      int tq = tap + 1, kn = kc;
      if (tq == taps) { tq = 0; ++kn; }
      issueB(p + 1, kn, tq);
      // in flight: B(p+1)=4 newest; drains B(p) and any A issued last phase
      asm volatile("s_waitcnt vmcnt(4)" ::: "memory");
    } else {
      asm volatile("s_waitcnt vmcnt(0)" ::: "memory");
    }
    __builtin_amdgcn_s_barrier();     // phase-p data visible to all waves
    asm volatile("" ::: "memory");

    const int dy = (taps == 9) ? (tap / 3 - 1) : 0;
    const int dx = (taps == 9) ? (tap - (tap / 3) * 3 - 1) : 0;
    const int sRow0 = (wq * 8 + dy + 1) * 18 + xl + dx + 1;
    const char* bLds = (const char*)Bs[p & 1];
    __builtin_amdgcn_s_setprio(1);
#pragma unroll
    for (int ks = 0; ks < 2; ++ks) {
      const int g = ks * 4 + kq;
      bf16x8 af[8], bfr[4];
#pragma unroll
      for (int mi = 0; mi < 8; ++mi) {
        int s = sRow0 + mi * 18;
        af[mi] = *(const bf16x8*)((const char*)As + s * 128 + ((g ^ (s & 7)) * 16));
      }
#pragma unroll
      for (int ni = 0; ni < 4; ++ni) {
        int rB = wn + ni * 16 + xl;
        bfr[ni] = *(const bf16x8*)(bLds + rB * 128 + ((g ^ (rB & 7)) * 16));
      }
#pragma unroll
      for (int mi = 0; mi < 8; ++mi)
#pragma unroll
        for (int ni = 0; ni < 4; ++ni)
          acc[mi][ni] = __builtin_amdgcn_mfma_f32_16x16x32_bf16(af[mi], bfr[ni], acc[mi][ni], 0, 0, 0);
    }
    __builtin_amdgcn_s_setprio(0);
    asm volatile("" ::: "memory");
    __builtin_amdgcn_s_barrier();     // all reads of phase-p buffers done

    if (tap == taps - 1 && kc + 1 < nA) issueA(kc + 1);  // safe: after the barrier
    if (++tap == taps) { tap = 0; ++kc; }
  }

  // ---- epilogue: BN + ReLU, store ----
  float sc[4], bi[4];
#pragma unroll
  for (int ni = 0; ni < 4; ++ni) {
    int cc = n0 + wn + ni * 16 + xl;
    sc[ni] = sb[cc];
    bi[ni] = sb[Cout + cc];
  }
#pragma unroll
  for (int mi = 0; mi < 8; ++mi) {
    int y = y0 + wq * 8 + mi;
    if (y >= BEV) continue;
#pragma unroll
    for (int j = 0; j < 4; ++j) {
      int x = x0c + kq * 4 + j;  // C/D layout: row = (lane>>4)*4 + j
      if (x >= BEV) continue;
      int pp = b * NPOS + y * BEV + x;
#pragma unroll
      for (int ni = 0; ni < 4; ++ni) {
        int cc = n0 + wn + ni * 16 + xl;
        float v = fmaxf(acc[mi][ni][j] * sc[ni] + bi[ni], 0.f);
        if (isFinal) {
          of32[((size_t)(b * Cout + cc)) * NPOS + (size_t)y * BEV + x] = v;
        } else {
          obf[(size_t)pp * Cout + cc] = __float2bfloat16(v);
        }
      }
    }
  }
}

extern "C" void kernel_launch(void* const* d_in, const int* in_sizes, int n_in,
                              void* d_out, int out_size, void* d_ws, size_t ws_size,
                              hipStream_t stream) {
  const float* radar = (const float*)d_in[0];
  const float* imgf = (const float*)d_in[1];
  const float* l2i = (const float*)d_in[2];
  const float* w1 = (const float*)d_in[3];
  const float* bn1 = (const float*)d_in[4];
  const float* w2 = (const float*)d_in[5];
  const float* bn2 = (const float*)d_in[6];
  const float* wf1 = (const float*)d_in[7];
  const float* bnf1 = (const float*)d_in[8];
  const float* wf2 = (const float*)d_in[9];
  const float* bnf2 = (const float*)d_in[10];

  char* ws = (char*)d_ws;
  size_t off = 0;
  auto alloc = [&](size_t bytes) {
    char* p = ws + off;
    off += (bytes + 255) & ~(size_t)255;
    return p;
  };
  char* zp = alloc(4096);
  char* imgT = alloc((size_t)2 * IH * IW * CIMG * 4);   // 23.0 MB fp32 NHWC
  char* ibev = alloc((size_t)MTOT * CIMG * 2);          // 33.2 MB bf16 NHWC
  char* radarT = imgT;                                  // alias: used after imgT/ibev dead
  char* h1 = alloc((size_t)MTOT * 384 * 2);             // 49.8 MB
  char* h2 = alloc((size_t)MTOT * 384 * 2);             // 49.8 MB
  char* f1 = h1;                                        // alias: h1 dead after conv2
  char* wp1 = alloc((size_t)1 * 384 * 256 * 2);
  char* wp2 = alloc((size_t)9 * 384 * 384 * 2);
  char* wpf1 = alloc((size_t)9 * 384 * 768 * 2);
  char* wpf2 = alloc((size_t)9 * 384 * 384 * 2);
  char* sb1 = alloc(2 * 384 * 4);
  char* sb2 = alloc(2 * 384 * 4);
  char* sbf1 = alloc(2 * 384 * 4);
  char* sbf2 = alloc(2 * 384 * 4);

  k_zero<<<1, 512, 0, stream>>>((unsigned long long*)zp);

  dim3 tb(32, 8);
  // img_feat NCHW -> NHWC fp32
  k_transpose<float><<<dim3((IH * IW + 31) / 32, (CIMG + 31) / 32, 2), tb, 0, stream>>>(
      imgf, (float*)imgT, CIMG, IH * IW);

  auto packw = [&](const float* src, char* dst, int Co, int Ci, int T) {
    size_t tot = (size_t)Co * Ci * T;
    k_packw<<<(unsigned)((tot + 255) / 256), 256, 0, stream>>>(src, (__hip_bfloat16*)dst, Co, Ci, T);
  };
  packw(w1, wp1, 384, 256, 1);
  packw(w2, wp2, 384, 384, 9);
  packw(wf1, wpf1, 384, 768, 9);
  packw(wf2, wpf2, 384, 384, 9);
  k_packbn<<<2, 256, 0, stream>>>(bn1, (float*)sb1, 384);
  k_packbn<<<2, 256, 0, stream>>>(bn2, (float*)sb2, 384);
  k_packbn<<<2, 256, 0, stream>>>(bnf1, (float*)sbf1, 384);
  k_packbn<<<2, 256, 0, stream>>>(bnf2, (float*)sbf2, 384);

  // sampling -> image_bev NHWC bf16
  k_sample<<<MTOT, 256, 0, stream>>>((const float*)imgT, l2i, (__hip_bfloat16*)ibev);

  dim3 cg(288, 3);   // 288 M-tiles (12x12 spatial x 2 batch) x 3 N-blocks
  // conv1: 1x1, image_bev(256) -> h1(384)
  k_conv<<<cg, 256, 0, stream>>>((const __hip_bfloat16*)ibev, nullptr, 256, 0,
                                 (const __hip_bfloat16*)wp1, (const float*)sb1, 1, 0,
                                 (__hip_bfloat16*)h1, nullptr, (const __hip_bfloat16*)zp);
  // radar NCHW -> NHWC bf16 (aliases imgT/ibev — both dead after conv1)
  k_transpose<__hip_bfloat16><<<dim3((NPOS + 31) / 32, (384 + 31) / 32, 2), tb, 0, stream>>>(
      radar, (__hip_bfloat16*)radarT, 384, NPOS);
  // conv2: 3x3, h1(384) -> h2(384)
  k_conv<<<cg, 256, 0, stream>>>((const __hip_bfloat16*)h1, nullptr, 384, 0,
                                 (const __hip_bfloat16*)wp2, (const float*)sb2, 9, 0,
                                 (__hip_bfloat16*)h2, nullptr, (const __hip_bfloat16*)zp);
  // convf1: 3x3, concat(radar, h2)(768) -> f1(384)
  k_conv<<<cg, 256, 0, stream>>>((const __hip_bfloat16*)radarT, (const __hip_bfloat16*)h2, 384, 384,
                                 (const __hip_bfloat16*)wpf1, (const float*)sbf1, 9, 0,
                                 (__hip_bfloat16*)f1, nullptr, (const __hip_bfloat16*)zp);
  // convf2: 3x3, f1(384) -> d_out fp32 NCHW
  k_conv<<<cg, 256, 0, stream>>>((const __hip_bfloat16*)f1, nullptr, 384, 0,
                                 (const __hip_bfloat16*)wpf2, (const float*)sbf2, 9, 1,
                                 nullptr, (float*)d_out, (const __hip_bfloat16*)zp);
}